// Round 2
// baseline (160.021 us; speedup 1.0000x reference)
//
#include <hip/hip_runtime.h>

#define NE 8
#define DIM 1024
#define ALPHA_C 10.0f

__global__ __launch_bounds__(256, 2) void topk_gating_kernel(
    const float* __restrict__ x,
    const float* __restrict__ gw,
    const float* __restrict__ gb,
    float* __restrict__ out,
    int nrows)
{
    const int tid = threadIdx.x;
    const int lane = tid & 63;
    const int wid = (blockIdx.x * blockDim.x + tid) >> 6;
    const int nwaves = (gridDim.x * blockDim.x) >> 6;

    // ---- Per-lane weight slice held in REGISTERS (no LDS in the hot loop).
    // Lane `l` owns float4s at positions l, l+64, l+128, l+192 of each expert
    // row -- exactly matching the coalesced x-load pattern below.
    // 8 experts x 4 float4 = 128 VGPR.
    float4 w[NE][4];
    #pragma unroll
    for (int e = 0; e < NE; ++e) {
        const float4* wr = (const float4*)(gw + e * DIM);
        #pragma unroll
        for (int j = 0; j < 4; ++j) w[e][j] = wr[lane + 64 * j];
    }

    float bias[NE];
    #pragma unroll
    for (int e = 0; e < NE; ++e) bias[e] = gb[e];

    // ---- Register double-buffer on x: prefetch row r+stride while computing r.
    int row = wid;
    float4 xa0, xa1, xa2, xa3;
    if (row < nrows) {
        const float4* xr = (const float4*)(x + (size_t)row * DIM);
        xa0 = xr[lane];
        xa1 = xr[lane + 64];
        xa2 = xr[lane + 128];
        xa3 = xr[lane + 192];
    }

    for (; row < nrows; row += nwaves) {
        const int nrow = row + nwaves;
        float4 xb0, xb1, xb2, xb3;
        if (nrow < nrows) {
            const float4* xr = (const float4*)(x + (size_t)nrow * DIM);
            xb0 = xr[lane];
            xb1 = xr[lane + 64];
            xb2 = xr[lane + 128];
            xb3 = xr[lane + 192];
        }

        float acc[NE];
        #pragma unroll
        for (int e = 0; e < NE; ++e) {
            float a;
            a  = xa0.x * w[e][0].x + xa0.y * w[e][0].y + xa0.z * w[e][0].z + xa0.w * w[e][0].w;
            a += xa1.x * w[e][1].x + xa1.y * w[e][1].y + xa1.z * w[e][1].z + xa1.w * w[e][1].w;
            a += xa2.x * w[e][2].x + xa2.y * w[e][2].y + xa2.z * w[e][2].z + xa2.w * w[e][2].w;
            a += xa3.x * w[e][3].x + xa3.y * w[e][3].y + xa3.z * w[e][3].z + xa3.w * w[e][3].w;
            acc[e] = a;
        }

        // Full butterfly reduce: afterwards EVERY lane holds all 8 logits.
        #pragma unroll
        for (int e = 0; e < NE; ++e) {
            float v = acc[e];
            #pragma unroll
            for (int m = 32; m >= 1; m >>= 1) v += __shfl_xor(v, m);
            acc[e] = v + bias[e];
        }

        // ---- epilogue, redundant on all lanes (values wave-uniform) ----
        // max and 2nd-largest (duplicate-preserving, matches top_k[:,1])
        float m1 = -INFINITY, m2 = -INFINITY;
        #pragma unroll
        for (int e = 0; e < NE; ++e) {
            float v = acc[e];
            float nm2 = fmaxf(m2, fminf(m1, v));
            m1 = fmaxf(m1, v);
            m2 = nm2;
        }

        // softmax of raw logits
        float ex[NE];
        float sum = 0.f;
        #pragma unroll
        for (int e = 0; e < NE; ++e) {
            ex[e] = __expf(acc[e] - m1);
            sum += ex[e];
        }
        float inv = 1.f / sum;

        // decomposition: (l < kth) -> ALPHA*log1p(s), else ALPHA*(exp(s)-1)
        float o[NE];
        #pragma unroll
        for (int e = 0; e < NE; ++e) {
            float s = ex[e] * inv;
            float topv = ALPHA_C * (__expf(s) - 1.f);
            float lowv = ALPHA_C * __logf(1.f + s);
            o[e] = (acc[e] >= m2) ? topv : lowv;
        }

        // final softmax
        float om = o[0];
        #pragma unroll
        for (int e = 1; e < NE; ++e) om = fmaxf(om, o[e]);
        float oex[NE];
        float osum = 0.f;
        #pragma unroll
        for (int e = 0; e < NE; ++e) {
            oex[e] = __expf(o[e] - om);
            osum += oex[e];
        }
        float oinv = 1.f / osum;

        // lane e writes gate[e]; compile-time-index select chain (no scratch)
        float gsel = oex[0] * oinv;
        #pragma unroll
        for (int e = 1; e < NE; ++e) {
            float ge = oex[e] * oinv;
            gsel = (lane == e) ? ge : gsel;
        }
        if (lane < NE) out[(size_t)row * NE + lane] = gsel;

        // rotate double buffer
        xa0 = xb0; xa1 = xb1; xa2 = xb2; xa3 = xb3;
    }
}

extern "C" void kernel_launch(void* const* d_in, const int* in_sizes, int n_in,
                              void* d_out, int out_size, void* d_ws, size_t ws_size,
                              hipStream_t stream) {
    const float* x  = (const float*)d_in[0];
    const float* gw = (const float*)d_in[1];
    const float* gb = (const float*)d_in[2];
    float* out = (float*)d_out;
    const int nrows = in_sizes[0] / DIM;

    const int block = 256;
    const int grid = 1024;   // 4096 waves -> 32 rows/wave at N=131072
    topk_gating_kernel<<<grid, block, 0, stream>>>(x, gw, gb, out, nrows);
}

// Round 3
// 152.535 us; speedup vs baseline: 1.0491x; 1.0491x over previous
//
#include <hip/hip_runtime.h>

#define NE 8
#define DIM 1024
#define ALPHA_C 10.0f

// 4 lanes per row, 16 rows per wave. W in LDS read via broadcast addresses.
__global__ __launch_bounds__(512, 4) void topk_gating_kernel(
    const float* __restrict__ x,
    const float* __restrict__ gw,
    const float* __restrict__ gb,
    float* __restrict__ out,
    int nrows)
{
    __shared__ float wlds[NE * DIM];   // 32 KiB

    const int tid = threadIdx.x;

    // Stage W into LDS, coalesced: 2048 float4 / 512 thr = 4 each
    {
        const float4* src = (const float4*)gw;
        float4* dst = (float4*)wlds;
        #pragma unroll
        for (int i = 0; i < 4; ++i)
            dst[tid + i * 512] = src[tid + i * 512];
    }
    float bias[NE];
    #pragma unroll
    for (int e = 0; e < NE; ++e) bias[e] = gb[e];
    __syncthreads();

    const int lane = tid & 63;
    const int g = lane >> 2;          // row-within-group-of-16
    const int s = lane & 3;           // sub-lane within row
    const int wid = (blockIdx.x * blockDim.x + tid) >> 6;
    const int nwaves = (gridDim.x * blockDim.x) >> 6;

    const float4* x4 = (const float4*)x;
    const float4* w4 = (const float4*)wlds;

    for (int base = wid * 16; base < nrows; base += nwaves * 16) {
        const int row = base + g;
        const bool valid = row < nrows;
        const size_t xoff = (size_t)row * (DIM / 4) + s;

        float acc[NE] = {0.f, 0.f, 0.f, 0.f, 0.f, 0.f, 0.f, 0.f};
        if (valid) {
            #pragma unroll 2
            for (int j = 0; j < 64; ++j) {
                // lanes of a group read 64 B contiguous; coalesced per group
                float4 xv = x4[xoff + j * 4];
                #pragma unroll
                for (int e = 0; e < NE; ++e) {
                    // only 4 unique addresses per wave instr -> broadcast, cheap
                    float4 wv = w4[e * (DIM / 4) + j * 4 + s];
                    acc[e] += xv.x * wv.x + xv.y * wv.y + xv.z * wv.z + xv.w * wv.w;
                }
            }
        }

        // Reduce across the 4 lanes of each group; all 4 end with full sums.
        #pragma unroll
        for (int e = 0; e < NE; ++e) {
            float v = acc[e];
            v += __shfl_xor(v, 1);
            v += __shfl_xor(v, 2);
            acc[e] = v + bias[e];
        }

        // ---- epilogue (redundant across the 4 lanes of a row) ----
        // max and 2nd-largest (duplicate-preserving == kthvalue semantics)
        float m1 = -INFINITY, m2 = -INFINITY;
        #pragma unroll
        for (int e = 0; e < NE; ++e) {
            float v = acc[e];
            float nm2 = fmaxf(m2, fminf(m1, v));
            m1 = fmaxf(m1, v);
            m2 = nm2;
        }

        // softmax of raw logits
        float ex[NE];
        float sum = 0.f;
        #pragma unroll
        for (int e = 0; e < NE; ++e) {
            ex[e] = __expf(acc[e] - m1);
            sum += ex[e];
        }
        float inv = 1.f / sum;

        // decomposition: (l < kth) -> ALPHA*log1p(s), else ALPHA*(exp(s)-1)
        float o[NE];
        #pragma unroll
        for (int e = 0; e < NE; ++e) {
            float sft = ex[e] * inv;
            float topv = ALPHA_C * (__expf(sft) - 1.f);
            float lowv = ALPHA_C * __logf(1.f + sft);
            o[e] = (acc[e] >= m2) ? topv : lowv;
        }

        // final softmax
        float om = o[0];
        #pragma unroll
        for (int e = 1; e < NE; ++e) om = fmaxf(om, o[e]);
        float oex[NE];
        float osum = 0.f;
        #pragma unroll
        for (int e = 0; e < NE; ++e) {
            oex[e] = __expf(o[e] - om);
            osum += oex[e];
        }
        float oinv = 1.f / osum;

        // lane s writes gates[2s], gates[2s+1] as float2 (coalesced per group)
        float ga = oex[0] * oinv;
        float gbv = oex[1] * oinv;
        #pragma unroll
        for (int e = 1; e < 4; ++e) {
            float ca = oex[2 * e] * oinv;
            float cb = oex[2 * e + 1] * oinv;
            ga  = (s == e) ? ca : ga;
            gbv = (s == e) ? cb : gbv;
        }
        if (valid)
            ((float2*)out)[(size_t)row * 4 + s] = make_float2(ga, gbv);
    }
}

extern "C" void kernel_launch(void* const* d_in, const int* in_sizes, int n_in,
                              void* d_out, int out_size, void* d_ws, size_t ws_size,
                              hipStream_t stream) {
    const float* x  = (const float*)d_in[0];
    const float* gw = (const float*)d_in[1];
    const float* gb = (const float*)d_in[2];
    float* out = (float*)d_out;
    const int nrows = in_sizes[0] / DIM;

    const int block = 512;   // 8 waves/block, 32 KiB LDS -> 4 blocks/CU possible
    const int grid = 1024;   // 8192 waves == 8192 groups of 16 rows at N=131072
    topk_gating_kernel<<<grid, block, 0, stream>>>(x, gw, gb, out, nrows);
}